// Round 6
// baseline (682.649 us; speedup 1.0000x reference)
//
#include <hip/hip_runtime.h>
#include <hip/hip_bf16.h>

#define CIN   128
#define EMBD  64
#define KC    512
#define SPAT  32768
#define NVOX  131072
#define QSZ   (NVOX * EMBD)      // 8388608
#define DIFF_OFF QSZ
#define IDX_OFF  (QSZ + 1)

// ---------------------------------------------------------------------------
// Prep A: embedT[k][o] = embed[o][k], norms[k] = ||e_k||^2
// ---------------------------------------------------------------------------
__global__ __launch_bounds__(64) void vq_prep(const float* __restrict__ embed,
                                              float* __restrict__ embedT,
                                              float* __restrict__ norms) {
  int k = blockIdx.x;   // 512
  int o = threadIdx.x;  // 64
  float e = embed[o * KC + k];
  embedT[k * EMBD + o] = e;
  float s = e * e;
  #pragma unroll
  for (int off = 32; off > 0; off >>= 1) s += __shfl_down(s, off);
  if (o == 0) norms[k] = s;
}

// Prep B: wT[c][o] = conv_w[o*128+c]  (contiguous 64-float rows -> s_load)
__global__ __launch_bounds__(256) void vq_prepw(const float* __restrict__ conv_w,
                                                float* __restrict__ wT) {
  int f = blockIdx.x * 256 + threadIdx.x;   // 8192
  int c = f >> 6;
  int o = f & 63;
  wT[f] = conv_w[o * CIN + c];
}

// ---------------------------------------------------------------------------
// Main: 2 threads per voxel, split over CODES (not components).
// threads 0-127 = k-half 0, threads 128-255 = k-half 1 (wave-uniform!).
// Both compute full z[64]; all conv_w / embedT / norms reads are
// wave-uniform -> compiler scalarizes to s_load (SGPR broadcast), keeping
// VGPRs for z[]. One LDS exchange at the end combines the two candidates.
// ---------------------------------------------------------------------------
__global__ __launch_bounds__(256, 4) void vq_main(
    const float* __restrict__ x, const float* __restrict__ wT,
    const float* __restrict__ conv_b, const float* __restrict__ embedT,
    const float* __restrict__ norms, float* __restrict__ out,
    float* __restrict__ partials) {
  __shared__ float best_sh[256];
  __shared__ int   bi_sh[256];
  __shared__ float red[4];

  const int tid  = threadIdx.x;
  const int half = tid >> 7;                  // k-half, uniform per wave
  const int vloc = tid & 127;
  const int n    = blockIdx.x * 128 + vloc;   // voxel id
  const int b    = n >> 15;
  const int v    = n & (SPAT - 1);

  const float* xp = x + ((size_t)b * CIN) * SPAT + v;

  // z = W x + b   (full 64-vector per thread; weights via wave-uniform loads)
  float z[EMBD];
  #pragma unroll
  for (int o = 0; o < EMBD; ++o) z[o] = conv_b[o];

  #pragma unroll 2
  for (int c = 0; c < CIN; ++c) {
    float xv = xp[(size_t)c * SPAT];          // coalesced across lanes
    const float* wr = wT + c * EMBD;          // wave-uniform
    #pragma unroll
    for (int o = 0; o < EMBD; ++o) z[o] = fmaf(xv, wr[o], z[o]);
  }

  // argmin over this thread's 256 codes: score = ||e_k||^2 - 2 z.e_k
  const int kbase = half * (KC / 2);
  float best = 3.4e38f;
  int bi = kbase;
  #pragma unroll 2
  for (int kk = 0; kk < KC / 2; ++kk) {
    const int k = kbase + kk;
    const float* ek = embedT + k * EMBD;      // wave-uniform
    float d0 = 0.f, d1 = 0.f, d2 = 0.f, d3 = 0.f;
    #pragma unroll
    for (int q = 0; q < 16; ++q) {
      float4 e4 = *(const float4*)(ek + q * 4);
      d0 = fmaf(z[q * 4 + 0], e4.x, d0);
      d1 = fmaf(z[q * 4 + 1], e4.y, d1);
      d2 = fmaf(z[q * 4 + 2], e4.z, d2);
      d3 = fmaf(z[q * 4 + 3], e4.w, d3);
    }
    float dot = (d0 + d1) + (d2 + d3);
    float s = fmaf(-2.f, dot, norms[k]);
    if (s < best) { best = s; bi = k; }       // strict < = first min
  }

  // combine the two k-half candidates (tie -> smaller index = half 0)
  best_sh[tid] = best;
  bi_sh[tid]   = bi;
  __syncthreads();
  float ob  = best_sh[tid ^ 128];
  int   obi = bi_sh[tid ^ 128];
  bool take = half ? (ob <= best) : (ob < best);
  const int biW = take ? obi : bi;

  // outputs: this thread writes its o-half of quantize + its diff share
  const int obase = half * 32;
  const float* eb = embedT + biW * EMBD + obase;
  float* qout = out + ((size_t)b * EMBD + obase) * SPAT + v;
  float diff = 0.f;
  #pragma unroll
  for (int i = 0; i < 32; ++i) {
    float e = eb[i];
    float r = e - z[obase + i];
    diff = fmaf(r, r, diff);
    qout[(size_t)i * SPAT] = e;               // coalesced per o across lanes
  }
  if (half == 0) out[IDX_OFF + n] = (float)biW;

  // block-reduce diff -> partials[block]
  #pragma unroll
  for (int off = 32; off > 0; off >>= 1) diff += __shfl_down(diff, off);
  if ((tid & 63) == 0) red[tid >> 6] = diff;
  __syncthreads();
  if (tid == 0)
    partials[blockIdx.x] = red[0] + red[1] + red[2] + red[3];
}

__global__ __launch_bounds__(512) void vq_final(const float* __restrict__ partials,
                                                float* __restrict__ out) {
  __shared__ float tmp[8];
  float s = partials[threadIdx.x] + partials[threadIdx.x + 512];  // 1024 partials
  #pragma unroll
  for (int off = 32; off > 0; off >>= 1) s += __shfl_down(s, off);
  if ((threadIdx.x & 63) == 0) tmp[threadIdx.x >> 6] = s;
  __syncthreads();
  if (threadIdx.x == 0) {
    float t = 0.f;
    #pragma unroll
    for (int i = 0; i < 8; ++i) t += tmp[i];
    out[DIFF_OFF] = t * (1.0f / (float)QSZ);
  }
}

extern "C" void kernel_launch(void* const* d_in, const int* in_sizes, int n_in,
                              void* d_out, int out_size, void* d_ws, size_t ws_size,
                              hipStream_t stream) {
  const float* x      = (const float*)d_in[0];
  const float* conv_w = (const float*)d_in[1];
  const float* conv_b = (const float*)d_in[2];
  const float* embed  = (const float*)d_in[3];
  float* out = (float*)d_out;
  float* ws  = (float*)d_ws;

  float* embedT   = ws;            // 32768 floats (128 KB)
  float* norms    = ws + 32768;    // 512
  float* wT       = ws + 33280;    // 8192
  float* partials = ws + 41472;    // 1024

  vq_prep<<<KC, EMBD, 0, stream>>>(embed, embedT, norms);
  vq_prepw<<<32, 256, 0, stream>>>(conv_w, wT);
  vq_main<<<NVOX / 128, 256, 0, stream>>>(x, wT, conv_b, embedT, norms,
                                          out, partials);
  vq_final<<<1, 512, 0, stream>>>(partials, out);
}

// Round 7
// 403.517 us; speedup vs baseline: 1.6917x; 1.6917x over previous
//
#include <hip/hip_runtime.h>
#include <hip/hip_bf16.h>

#define CIN   128
#define EMBD  64
#define KC    512
#define SPAT  32768
#define NVOX  131072
#define QSZ   (NVOX * EMBD)      // 8388608
#define DIFF_OFF QSZ
#define IDX_OFF  (QSZ + 1)
#define NBLK  (NVOX / 64)        // 2048 blocks, 64 voxels each

typedef __attribute__((ext_vector_type(8))) short bf16x8;
typedef __attribute__((ext_vector_type(4))) float f32x4;

__device__ __forceinline__ short bf_hi(float f) {
  __hip_bfloat16 h = __float2bfloat16(f);
  return *(short*)&h;
}
__device__ __forceinline__ float bf_f(short s) {
  __hip_bfloat16 h = *(__hip_bfloat16*)&s;
  return __bfloat162float(h);
}

// ---------------------------------------------------------------------------
// Prep E: embedT[k][o] (f32 rows), norms[k], and 3-way bf16 split e_h/e_m/e_l
// as [code][64] bf16 row-major (K-contiguous for MFMA B-frags).
// ---------------------------------------------------------------------------
__global__ __launch_bounds__(64) void vq_prep_e(const float* __restrict__ embed,
                                                float* __restrict__ embedT,
                                                float* __restrict__ norms,
                                                short* __restrict__ e_h,
                                                short* __restrict__ e_m,
                                                short* __restrict__ e_l) {
  int k = blockIdx.x;   // code 0..511
  int o = threadIdx.x;  // emb 0..63
  float e = embed[o * KC + k];
  embedT[k * EMBD + o] = e;
  short h = bf_hi(e);
  float r1 = e - bf_f(h);
  short m = bf_hi(r1);
  short l = bf_hi(r1 - bf_f(m));
  e_h[k * EMBD + o] = h;
  e_m[k * EMBD + o] = m;
  e_l[k * EMBD + o] = l;
  float s = e * e;
  #pragma unroll
  for (int off = 32; off > 0; off >>= 1) s += __shfl_down(s, off);
  if (o == 0) norms[k] = s;
}

// Prep W: wT[c][o] = conv_w[o*128+c]  (o-contiguous rows -> wave-uniform s_load)
__global__ __launch_bounds__(256) void vq_prep_w(const float* __restrict__ conv_w,
                                                 float* __restrict__ wT) {
  int f = blockIdx.x * 256 + threadIdx.x;   // 8192
  int c = f >> 6;
  int o = f & 63;
  wT[f] = conv_w[o * CIN + c];
}

// ---------------------------------------------------------------------------
// Main: 64 voxels/block, 256 threads (4 waves).
// Phase 1 (VALU): z = Wx+b exact f32; 4 waves = 4 o-quarters; 3-split z into
//   swizzled LDS. Phase 2 (MFMA): scores for all 512 codes, 6 split-passes,
//   fused argmin. Epilogue: idx, diff = best_score + ||z||^2, gather quantize.
// ---------------------------------------------------------------------------
__global__ __launch_bounds__(256, 2) void vq_main(
    const float* __restrict__ x, const float* __restrict__ wT,
    const float* __restrict__ conv_b, const float* __restrict__ embedT,
    const short* __restrict__ e_h, const short* __restrict__ e_m,
    const short* __restrict__ e_l, const float* __restrict__ norms,
    float* __restrict__ out, float* __restrict__ partials) {
  __shared__ short zh[64 * 64], zm[64 * 64], zl[64 * 64];  // swizzled, 8KB each
  __shared__ float norml[KC];
  __shared__ float zsq4[64][4];
  __shared__ float wbest[4][64];
  __shared__ int   widx[4][64];
  __shared__ int   fidx[64];

  const int t    = threadIdx.x;
  const int q    = t >> 6;        // wave id = o-quarter (phase 1) = code-quarter (phase 2)
  const int v    = t & 63;        // voxel within block (phase 1)
  const int n0   = blockIdx.x * 64;
  const int b    = n0 >> 15;
  const int vsp  = n0 & (SPAT - 1);

  // stage norms
  norml[t]       = norms[t];
  norml[t + 256] = norms[t + 256];

  // ---- Phase 1: conv ----
  const float* xp = x + ((size_t)b * CIN) * SPAT + vsp + v;
  float z[16];
  #pragma unroll
  for (int j = 0; j < 16; ++j) z[j] = conv_b[q * 16 + j];

  #pragma unroll 4
  for (int c = 0; c < CIN; ++c) {
    float xv = xp[(size_t)c * SPAT];           // 256B coalesced per wave
    const float* wr = wT + c * EMBD + q * 16;  // wave-uniform -> s_load
    #pragma unroll
    for (int j = 0; j < 16; ++j) z[j] = fmaf(xv, wr[j], z[j]);
  }

  float sq = 0.f;
  #pragma unroll
  for (int j = 0; j < 16; ++j) sq = fmaf(z[j], z[j], sq);
  zsq4[v][q] = sq;

  // 3-way bf16 split -> swizzled LDS ([vox][64] bf16, 16B-subblock s ^= vox&7)
  short h16[16], m16[16], l16[16];
  #pragma unroll
  for (int j = 0; j < 16; ++j) {
    short h = bf_hi(z[j]);
    float r1 = z[j] - bf_f(h);
    short m = bf_hi(r1);
    h16[j] = h; m16[j] = m; l16[j] = bf_hi(r1 - bf_f(m));
  }
  #pragma unroll
  for (int jj = 0; jj < 2; ++jj) {
    int s = (2 * q + jj) ^ (v & 7);
    int byte = v * 128 + s * 16;
    bf16x8 hv, mv, lv;
    #pragma unroll
    for (int j = 0; j < 8; ++j) { hv[j] = h16[jj*8+j]; mv[j] = m16[jj*8+j]; lv[j] = l16[jj*8+j]; }
    *(bf16x8*)((char*)zh + byte) = hv;
    *(bf16x8*)((char*)zm + byte) = mv;
    *(bf16x8*)((char*)zl + byte) = lv;
  }
  __syncthreads();

  // ---- Phase 2: distances via MFMA ----
  const int lane = t & 63;
  const int l15  = lane & 15;
  const int g    = lane >> 4;            // k-group 0..3

  f32x4 acc[4][8];
  #pragma unroll
  for (int m = 0; m < 4; ++m)
    #pragma unroll
    for (int n = 0; n < 8; ++n) { f32x4 z4 = {0.f,0.f,0.f,0.f}; acc[m][n] = z4; }

  // B byte offset: code = q*128 + n*16 + l15; addr = code*128 + ks8*16 + g*16
  const int boff = (q * 128 + l15) * 128 + g * 16;

  auto dist_pass = [&](const short* zlds, const short* __restrict__ eg) {
    #pragma unroll
    for (int ks8 = 0; ks8 <= 4; ks8 += 4) {   // k-step 0 / 32 (subblock 0/4)
      bf16x8 a[4];
      #pragma unroll
      for (int m = 0; m < 4; ++m) {
        int vox = m * 16 + l15;
        a[m] = *(const bf16x8*)((const char*)zlds + vox * 128 +
                                (((ks8 + g) ^ (vox & 7)) << 4));
      }
      #pragma unroll
      for (int n = 0; n < 8; ++n) {
        bf16x8 bb = *(const bf16x8*)((const char*)eg + boff + n * 2048 + ks8 * 16);
        #pragma unroll
        for (int m = 0; m < 4; ++m)
          acc[m][n] = __builtin_amdgcn_mfma_f32_16x16x32_bf16(a[m], bb, acc[m][n], 0, 0, 0);
      }
    }
  };
  // 6 split passes: hh, hm, mh, hl, lh, mm  (residual ~2^-18 dropped)
  dist_pass(zh, e_h);
  dist_pass(zh, e_m);
  dist_pass(zm, e_h);
  dist_pass(zh, e_l);
  dist_pass(zl, e_h);
  dist_pass(zm, e_m);

  // ---- fused argmin (scores = norms - 2*dot) ----
  float nv[8];
  #pragma unroll
  for (int n = 0; n < 8; ++n) nv[n] = norml[q * 128 + n * 16 + l15];

  float best[16]; int bidx[16];
  #pragma unroll
  for (int i = 0; i < 16; ++i) { best[i] = 3.4e38f; bidx[i] = 0; }
  #pragma unroll
  for (int n = 0; n < 8; ++n)
    #pragma unroll
    for (int m = 0; m < 4; ++m)
      #pragma unroll
      for (int r = 0; r < 4; ++r) {
        float s = fmaf(-2.f, acc[m][n][r], nv[n]);
        int code = q * 128 + n * 16 + l15;
        int i = m * 4 + r;
        bool tk = s < best[i];               // ascending n -> first-min kept
        best[i] = tk ? s : best[i];
        bidx[i] = tk ? code : bidx[i];
      }
  #pragma unroll
  for (int i = 0; i < 16; ++i) {
    #pragma unroll
    for (int d = 1; d < 16; d <<= 1) {
      float os = __shfl_xor(best[i], d);
      int   oi = __shfl_xor(bidx[i], d);
      bool tk = (os < best[i]) || (os == best[i] && oi < bidx[i]);
      best[i] = tk ? os : best[i];
      bidx[i] = tk ? oi : bidx[i];
    }
  }
  if (l15 == 0) {
    #pragma unroll
    for (int i = 0; i < 16; ++i) {
      int vox = (i >> 2) * 16 + g * 4 + (i & 3);
      wbest[q][vox] = best[i];
      widx[q][vox]  = bidx[i];
    }
  }
  __syncthreads();

  // ---- combine waves, idx + diff outputs ----
  if (t < 64) {
    float bs = wbest[0][t]; int bi = widx[0][t];
    #pragma unroll
    for (int w2 = 1; w2 < 4; ++w2) {
      float s2 = wbest[w2][t]; int i2 = widx[w2][t];
      bool tk = (s2 < bs) || (s2 == bs && i2 < bi);  // ascending code ranges
      bs = tk ? s2 : bs; bi = tk ? i2 : bi;
    }
    fidx[t] = bi;
    out[IDX_OFF + n0 + t] = (float)bi;
    float d = bs + zsq4[t][0] + zsq4[t][1] + zsq4[t][2] + zsq4[t][3];
    #pragma unroll
    for (int off = 32; off > 0; off >>= 1) d += __shfl_down(d, off);
    if (t == 0) partials[blockIdx.x] = d;
  }
  __syncthreads();

  // ---- quantize gather/write: thread t -> voxel v, o-quarter q ----
  const int bi = fidx[v];
  const float* er = embedT + bi * EMBD + q * 16;
  float* qout = out + ((size_t)b * EMBD + q * 16) * SPAT + vsp + v;
  #pragma unroll
  for (int u = 0; u < 4; ++u) {
    float4 e4 = *(const float4*)(er + u * 4);
    qout[(size_t)(u * 4 + 0) * SPAT] = e4.x;
    qout[(size_t)(u * 4 + 1) * SPAT] = e4.y;
    qout[(size_t)(u * 4 + 2) * SPAT] = e4.z;
    qout[(size_t)(u * 4 + 3) * SPAT] = e4.w;
  }
}

__global__ __launch_bounds__(512) void vq_final(const float* __restrict__ partials,
                                                float* __restrict__ out) {
  __shared__ float tmp[8];
  float s = partials[threadIdx.x] + partials[threadIdx.x + 512] +
            partials[threadIdx.x + 1024] + partials[threadIdx.x + 1536];
  #pragma unroll
  for (int off = 32; off > 0; off >>= 1) s += __shfl_down(s, off);
  if ((threadIdx.x & 63) == 0) tmp[threadIdx.x >> 6] = s;
  __syncthreads();
  if (threadIdx.x == 0) {
    float t = 0.f;
    #pragma unroll
    for (int i = 0; i < 8; ++i) t += tmp[i];
    out[DIFF_OFF] = t * (1.0f / (float)QSZ);
  }
}

extern "C" void kernel_launch(void* const* d_in, const int* in_sizes, int n_in,
                              void* d_out, int out_size, void* d_ws, size_t ws_size,
                              hipStream_t stream) {
  const float* x      = (const float*)d_in[0];
  const float* conv_w = (const float*)d_in[1];
  const float* conv_b = (const float*)d_in[2];
  const float* embed  = (const float*)d_in[3];
  float* out = (float*)d_out;
  float* ws  = (float*)d_ws;

  float* embedT   = ws;              // 32768 f32
  float* norms    = ws + 32768;      // 512
  float* wT       = ws + 33280;      // 8192
  float* partials = ws + 41472;      // 2048
  short* e_h      = (short*)(ws + 43520);   // 32768 bf16
  short* e_m      = e_h + KC * EMBD;
  short* e_l      = e_m + KC * EMBD;        // total ~371 KB of ws

  vq_prep_e<<<KC, EMBD, 0, stream>>>(embed, embedT, norms, e_h, e_m, e_l);
  vq_prep_w<<<32, 256, 0, stream>>>(conv_w, wT);
  vq_main<<<NBLK, 256, 0, stream>>>(x, wT, conv_b, embedT, e_h, e_m, e_l,
                                    norms, out, partials);
  vq_final<<<1, 512, 0, stream>>>(partials, out);
}